// Round 2
// baseline (486.951 us; speedup 1.0000x reference)
//
#include <hip/hip_runtime.h>
#include <hip/hip_bf16.h>

// Problem constants
#define B_   64
#define C_   3129
#define K_   10
#define DF_  768
#define F_   676      // 26*26
#define DW_  300
#define DWP_ 320      // DW_ padded to multiple of 64 (MFMA K-tile)
#define DT_  1024
#define NSEG 13       // o_bap f-segments: 676 = 13*52 (832 blocks -> 3.25/CU)
#define FSEG 52

typedef __attribute__((ext_vector_type(8))) short short8;   // 8 bf16
typedef __attribute__((ext_vector_type(4))) float floatx4;  // 4 fp32

// async 16B global -> LDS (wave-uniform LDS base + lane*16)
__device__ __forceinline__ void gload_lds16(const void* g, void* l) {
    __builtin_amdgcn_global_load_lds(
        (const __attribute__((address_space(1))) void*)g,
        (__attribute__((address_space(3))) void*)l, 16, 0, 0);
}

// ---------------------------------------------------------------------------
// 1. top-k (K=10) per row of logits [B, C], exact lax.top_k order.
__global__ void topk_kernel(const float* __restrict__ logits,
                            int* __restrict__ topk_idx) {
    __shared__ float vals[C_];
    __shared__ float red_v[256];
    __shared__ int   red_i[256];
    int b = blockIdx.x;
    int tid = threadIdx.x;
    for (int i = tid; i < C_; i += 256) vals[i] = logits[(size_t)b * C_ + i];
    __syncthreads();
    for (int sel = 0; sel < K_; ++sel) {
        float bv = -INFINITY; int bi = 0x7fffffff;
        for (int i = tid; i < C_; i += 256) {
            float v = vals[i];
            if (v > bv) { bv = v; bi = i; }
        }
        red_v[tid] = bv; red_i[tid] = bi;
        __syncthreads();
        for (int s = 128; s > 0; s >>= 1) {
            if (tid < s) {
                float ov = red_v[tid + s]; int oi = red_i[tid + s];
                if (ov > red_v[tid] || (ov == red_v[tid] && oi < red_i[tid])) {
                    red_v[tid] = ov; red_i[tid] = oi;
                }
            }
            __syncthreads();
        }
        if (tid == 0) {
            topk_idx[b * K_ + sel] = red_i[0];
            vals[red_i[0]] = -INFINITY;
        }
        __syncthreads();
    }
}

// ---------------------------------------------------------------------------
// 2. emb[bk][j] (bf16, K-padded to DWP_ with zeros)
__global__ void emb_kernel(const int* __restrict__ topk_idx,
                           const int* __restrict__ indices_table,
                           const float* __restrict__ word2vec,
                           __hip_bfloat16* __restrict__ emb) {
    int idx = blockIdx.x * blockDim.x + threadIdx.x;
    if (idx >= B_ * K_ * DWP_) return;
    int j  = idx % DWP_;
    int bk = idx / DWP_;
    float s = 0.f;
    if (j < DW_) {
        int cls = topk_idx[bk];
        const int* tbl = indices_table + (size_t)cls * 4;
        #pragma unroll
        for (int i = 0; i < 4; ++i) s += word2vec[(size_t)tbl[i] * DW_ + j];
        s *= 0.25f;
    }
    emb[idx] = (__hip_bfloat16)s;
}

// ---------------------------------------------------------------------------
// Transpose body: src[R][Cc] fp32 -> dst[Cc][Rp] bf16, zero-padded rows >= R.
__device__ __forceinline__ void tp_body(const float* __restrict__ s,
                                        __hip_bfloat16* __restrict__ d,
                                        int R, int Cc, int Rp, int c0, int r0) {
    __shared__ float tile[64][65];
    int t = threadIdx.x;
    int cl = (t & 15) * 4;
    int rl = t >> 4;
    #pragma unroll
    for (int i = 0; i < 4; ++i) {
        int r = rl + i * 16;
        float4 v = make_float4(0.f, 0.f, 0.f, 0.f);
        if (r0 + r < R && c0 + cl < Cc)
            v = *(const float4*)(s + (size_t)(r0 + r) * Cc + c0 + cl);
        tile[r][cl + 0] = v.x; tile[r][cl + 1] = v.y;
        tile[r][cl + 2] = v.z; tile[r][cl + 3] = v.w;
    }
    __syncthreads();
    int cw = t >> 2;
    int r4 = (t & 3) * 16;
    if (c0 + cw < Cc) {
        __align__(16) __hip_bfloat16 buf[16];
        #pragma unroll
        for (int j = 0; j < 16; ++j) buf[j] = (__hip_bfloat16)tile[r4 + j][cw];
        float4* dp = (float4*)(d + (size_t)(c0 + cw) * Rp + r0 + r4);
        dp[0] = *(float4*)&buf[0];
        dp[1] = *(float4*)&buf[8];
    }
}

// ftm transpose (z-batched)
__global__ __launch_bounds__(256)
void transpose_ftm(const float* __restrict__ src, __hip_bfloat16* __restrict__ dst) {
    tp_body(src + (size_t)blockIdx.z * DF_ * F_,
            dst + (size_t)blockIdx.z * F_ * DF_,
            DF_, F_, DF_, blockIdx.x * 64, blockIdx.y * 64);
}

// all 4 weight transposes in one dispatch (tile ranges hard-coded)
// W_emb: 16x5=80 | W_cls: 16x16=256 | W_v: 16x12=192 | W_bap: 256 -> 784
__global__ __launch_bounds__(256)
void transpose_weights(const float* __restrict__ Wemb, __hip_bfloat16* __restrict__ WembT,
                       const float* __restrict__ Wcls, __hip_bfloat16* __restrict__ WclsT,
                       const float* __restrict__ Wv,   __hip_bfloat16* __restrict__ WvT,
                       const float* __restrict__ Wbap, __hip_bfloat16* __restrict__ WbapT) {
    int id = blockIdx.x;
    const float* s; __hip_bfloat16* d; int R, Rp;
    if (id < 80)       { s = Wemb; d = WembT; R = DW_;  Rp = DWP_; }
    else if (id < 336) { s = Wcls; d = WclsT; R = DT_;  Rp = DT_;  id -= 80;  }
    else if (id < 528) { s = Wv;   d = WvT;   R = DF_;  Rp = DF_;  id -= 336; }
    else               { s = Wbap; d = WbapT; R = DT_;  Rp = DT_;  id -= 528; }
    int bx = id & 15;        // Cc = 1024 -> 16 col tiles for all mats
    int by = id >> 4;
    tp_body(s, d, R, DT_, Rp, bx * 64, by * 64);
}

// ---------------------------------------------------------------------------
// MFMA bf16 GEMM (128x128 tile, 2-phase): used for small GEMMs (cls, bap)
// and as fallback when M % 256 != 0.
template <int RELU, int OUTBF>
__global__ __launch_bounds__(256)
void gemm_mfma(const __hip_bfloat16* __restrict__ A,
               const __hip_bfloat16* __restrict__ Bt,
               const float* __restrict__ bias,
               void* __restrict__ Cout, int M, int N, int Kp) {
    __shared__ __align__(16) char smem[34816];       // max(As+Bs, C-tile 128x136)
    __hip_bfloat16* As = (__hip_bfloat16*)smem;      // [128][64]
    __hip_bfloat16* Bs = As + 128 * 64;              // [128][64]
    int tid = threadIdx.x;
    int wave = tid >> 6, lane = tid & 63;
    int quad = lane >> 4, l16 = lane & 15;
    int wm = (wave & 1) * 64, wn = (wave >> 1) * 64;

    // XCD-aware bijective remap (m204)
    int gx = gridDim.x;
    int nwg = gx * gridDim.y;
    int flat = blockIdx.y * gx + blockIdx.x;
    int q = nwg >> 3, r = nwg & 7;
    int xcd = flat & 7, lid = flat >> 3;
    int o = (xcd < r ? xcd * (q + 1) : r * (q + 1) + (xcd - r) * q) + lid;
    int n0 = (o % gx) * 128;
    int m0 = (o / gx) * 128;

    floatx4 acc[4][4];
    #pragma unroll
    for (int i = 0; i < 4; ++i)
        #pragma unroll
        for (int j = 0; j < 4; ++j)
            acc[i][j] = (floatx4){0.f, 0.f, 0.f, 0.f};

    int rsub = lane >> 3;
    int gchunk = (lane & 7) ^ rsub;

    int arow[4], brow[4];
    #pragma unroll
    for (int i = 0; i < 4; ++i) {
        arow[i] = wm + i * 16 + l16;
        brow[i] = wn + i * 16 + l16;
    }

    for (int k0 = 0; k0 < Kp; k0 += 64) {
        #pragma unroll
        for (int c = 0; c < 4; ++c) {
            int grp = wave * 4 + c;
            int row = grp * 8 + rsub;
            int ra = m0 + row; if (ra >= M) ra = M - 1;   // clamp: junk unused
            gload_lds16(A + (size_t)ra * Kp + k0 + gchunk * 8, As + grp * 512);
            gload_lds16(Bt + (size_t)(n0 + row) * Kp + k0 + gchunk * 8, Bs + grp * 512);
        }
        __syncthreads();
        #pragma unroll
        for (int ks = 0; ks < 2; ++ks) {
            short8 af[4], bf[4];
            #pragma unroll
            for (int mi = 0; mi < 4; ++mi)
                af[mi] = *(const short8*)&As[arow[mi] * 64 +
                            ((((ks << 2) | quad) ^ (arow[mi] & 7)) << 3)];
            #pragma unroll
            for (int ni = 0; ni < 4; ++ni)
                bf[ni] = *(const short8*)&Bs[brow[ni] * 64 +
                            ((((ks << 2) | quad) ^ (brow[ni] & 7)) << 3)];
            #pragma unroll
            for (int mi = 0; mi < 4; ++mi)
                #pragma unroll
                for (int ni = 0; ni < 4; ++ni)
                    acc[mi][ni] = __builtin_amdgcn_mfma_f32_16x16x32_bf16(
                        af[mi], bf[ni], acc[mi][ni], 0, 0, 0);
        }
        __syncthreads();
    }

    // C/D mapping: col = lane&15, row = quad*4 + reg  [measured m89/m91]
    float bn[4];
    #pragma unroll
    for (int ni = 0; ni < 4; ++ni) bn[ni] = bias[n0 + wn + ni * 16 + l16];

    if (OUTBF) {
        __hip_bfloat16* Cs = (__hip_bfloat16*)smem;
        #pragma unroll
        for (int mi = 0; mi < 4; ++mi)
            #pragma unroll
            for (int rr = 0; rr < 4; ++rr) {
                int row = wm + mi * 16 + quad * 4 + rr;
                #pragma unroll
                for (int ni = 0; ni < 4; ++ni) {
                    float val = acc[mi][ni][rr] + bn[ni];
                    if (RELU) val = fmaxf(val, 0.f);
                    Cs[row * 136 + wn + ni * 16 + l16] = (__hip_bfloat16)val;
                }
            }
        __syncthreads();
        #pragma unroll
        for (int j = 0; j < 8; ++j) {
            int ch = tid + 256 * j;              // 2048 chunks of 16 B
            int row = ch >> 4, c16 = ch & 15;
            int r = m0 + row;
            float4 val = *(const float4*)&Cs[row * 136 + c16 * 8];
            if (r < M)
                *(float4*)((__hip_bfloat16*)Cout + (size_t)r * N + n0 + c16 * 8) = val;
        }
    } else {
        #pragma unroll
        for (int mi = 0; mi < 4; ++mi)
            #pragma unroll
            for (int rr = 0; rr < 4; ++rr) {
                int r = m0 + wm + mi * 16 + quad * 4 + rr;
                if (r < M) {
                    #pragma unroll
                    for (int ni = 0; ni < 4; ++ni) {
                        float val = acc[mi][ni][rr] + bn[ni];
                        if (RELU) val = fmaxf(val, 0.f);
                        ((float*)Cout)[(size_t)r * N + n0 + wn + ni * 16 + l16] = val;
                    }
                }
            }
    }
}

// ---------------------------------------------------------------------------
// 256x256 phase-split MFMA GEMM (T2+T3+T4+T5): 8 waves (2M x 4N), BK=64,
// double-buffered 128 KiB LDS, 4 quadrant-phases per K-tile with raw
// s_barrier clustering + setprio around MFMA, next-tile prefetch kept in
// flight across barriers with counted vmcnt(8) (never 0 in steady state).
// Requires M%256==0, N%256==0, Kp%64==0. bf16 out, ReLU+bias fused.
__global__ __launch_bounds__(512, 2)
void gemm_mfma256(const __hip_bfloat16* __restrict__ A,
                  const __hip_bfloat16* __restrict__ Bt,
                  const float* __restrict__ bias,
                  __hip_bfloat16* __restrict__ Cout, int M, int N, int Kp) {
    // [buf][A 256x64 | B 256x64] ; buf stride 32768 bf16 = 64 KiB
    __shared__ __align__(16) __hip_bfloat16 smem[65536];   // 128 KiB
    int tid = threadIdx.x;
    int wave = tid >> 6, lane = tid & 63;
    int quad = lane >> 4, l16 = lane & 15;
    int wr = wave >> 2, wc = wave & 3;       // 2M x 4N wave grid

    // XCD-aware bijective remap (m204)
    int gx = gridDim.x;
    int nwg = gx * gridDim.y;
    int flat = blockIdx.y * gx + blockIdx.x;
    int q = nwg >> 3, r = nwg & 7;
    int xcd = flat & 7, lid = flat >> 3;
    int o = (xcd < r ? xcd * (q + 1) : r * (q + 1) + (xcd - r) * q) + lid;
    int n0 = (o % gx) * 256;
    int m0 = (o / gx) * 256;

    floatx4 acc[8][4];
    #pragma unroll
    for (int i = 0; i < 8; ++i)
        #pragma unroll
        for (int j = 0; j < 4; ++j)
            acc[i][j] = (floatx4){0.f, 0.f, 0.f, 0.f};

    // staging geometry: group g (0..31) = 8 rows (1024 B); wave issues
    // c=0..3 -> g = wave*4+c. lane: row-in-group = lane>>3, LDS chunk slot
    // lane&7; global chunk = slot ^ rowsub (involution swizzle on source,
    // LDS dest lane-linear).
    int rsub = lane >> 3;
    int gchunk = (lane & 7) ^ rsub;

    // fragment addressing (element offsets into 256x64 tile)
    int rowA[8], rowB[4], kchunk[2];
    #pragma unroll
    for (int i = 0; i < 8; ++i) rowA[i] = (wr * 128 + i * 16 + l16) * 64;
    #pragma unroll
    for (int i = 0; i < 4; ++i) rowB[i] = (wc * 64 + i * 16 + l16) * 64;
    #pragma unroll
    for (int ks = 0; ks < 2; ++ks)
        kchunk[ks] = ((((ks << 2) | quad) ^ (l16 & 7)) << 3);

    const int NT = Kp >> 6;

    // prologue: stage tile 0 -> buf 0
    {
        __hip_bfloat16* Ad = smem;
        __hip_bfloat16* Bd = smem + 16384;
        #pragma unroll
        for (int c = 0; c < 4; ++c) {
            int g = wave * 4 + c;
            int row = g * 8 + rsub;
            gload_lds16(A + (size_t)(m0 + row) * Kp + gchunk * 8, Ad + g * 512);
            gload_lds16(Bt + (size_t)(n0 + row) * Kp + gchunk * 8, Bd + g * 512);
        }
    }

    for (int kt = 0; kt < NT; ++kt) {
        int cur = kt & 1;
        // prefetch next tile into the other buffer (its readers finished at
        // the previous tile's trailing barrier), then wait for CURRENT tile's
        // 8 loads (oldest) -- counted, never draining the new 8.
        if (kt + 1 < NT) {
            __hip_bfloat16* Ad = smem + (cur ^ 1) * 32768;
            __hip_bfloat16* Bd = Ad + 16384;
            int k0n = (kt + 1) << 6;
            #pragma unroll
            for (int c = 0; c < 4; ++c) {
                int g = wave * 4 + c;
                int row = g * 8 + rsub;
                gload_lds16(A + (size_t)(m0 + row) * Kp + k0n + gchunk * 8,
                            Ad + g * 512);
                gload_lds16(Bt + (size_t)(n0 + row) * Kp + k0n + gchunk * 8,
                            Bd + g * 512);
            }
            asm volatile("s_waitcnt vmcnt(8)" ::: "memory");
        } else {
            asm volatile("s_waitcnt vmcnt(0)" ::: "memory");
        }
        __builtin_amdgcn_s_barrier();

        const __hip_bfloat16* As = smem + cur * 32768;
        const __hip_bfloat16* Bs = As + 16384;

        short8 af[4][2], bf2[2][2];
        #pragma unroll
        for (int ph = 0; ph < 4; ++ph) {
            const int h = ph >> 1, j = ph & 1;
            if (j == 0) {
                #pragma unroll
                for (int mi = 0; mi < 4; ++mi)
                    #pragma unroll
                    for (int ks = 0; ks < 2; ++ks)
                        af[mi][ks] = *(const short8*)&As[rowA[h * 4 + mi] + kchunk[ks]];
            }
            #pragma unroll
            for (int ni = 0; ni < 2; ++ni)
                #pragma unroll
                for (int ks = 0; ks < 2; ++ks)
                    bf2[ni][ks] = *(const short8*)&Bs[rowB[j * 2 + ni] + kchunk[ks]];
            __builtin_amdgcn_s_barrier();
            __builtin_amdgcn_s_setprio(1);
            #pragma unroll
            for (int ks = 0; ks < 2; ++ks)
                #pragma unroll
                for (int mi = 0; mi < 4; ++mi)
                    #pragma unroll
                    for (int ni = 0; ni < 2; ++ni)
                        acc[h * 4 + mi][j * 2 + ni] =
                            __builtin_amdgcn_mfma_f32_16x16x32_bf16(
                                af[mi][ks], bf2[ni][ks],
                                acc[h * 4 + mi][j * 2 + ni], 0, 0, 0);
            __builtin_amdgcn_s_setprio(0);
            __builtin_amdgcn_s_barrier();
        }
    }

    // epilogue: bias + relu -> bf16, staged through LDS in two 128-row
    // halves (stride 264 bf16), coalesced 16B stores.
    float bn[4];
    #pragma unroll
    for (int ni = 0; ni < 4; ++ni) bn[ni] = bias[n0 + wc * 64 + ni * 16 + l16];

    __hip_bfloat16* Cs = smem;                 // 128 x 264 bf16 = 66 KiB
    #pragma unroll
    for (int half = 0; half < 2; ++half) {
        if (wr == half) {
            #pragma unroll
            for (int mi = 0; mi < 8; ++mi)
                #pragma unroll
                for (int rr = 0; rr < 4; ++rr) {
                    int row = mi * 16 + quad * 4 + rr;
                    #pragma unroll
                    for (int ni = 0; ni < 4; ++ni) {
                        float val = acc[mi][ni][rr] + bn[ni];
                        val = fmaxf(val, 0.f);
                        Cs[row * 264 + wc * 64 + ni * 16 + l16] = (__hip_bfloat16)val;
                    }
                }
        }
        __syncthreads();
        #pragma unroll
        for (int s = 0; s < 8; ++s) {
            int ch = tid + 512 * s;            // 4096 chunks of 16 B
            int row = ch >> 5, c32 = ch & 31;
            float4 val = *(const float4*)&Cs[row * 264 + c32 * 8];
            *(float4*)(Cout + (size_t)(m0 + half * 128 + row) * N + n0 + c32 * 8) = val;
        }
        __syncthreads();
    }
}

// ---------------------------------------------------------------------------
// 4. s[bc,f,k] = sum_d v[bc,f,d] * cls[b0+bc,k,d]; 2 f per wave (halves cls
//    L2 traffic).
__global__ __launch_bounds__(256)
void attn_s_kernel(const __hip_bfloat16* __restrict__ v_buf,
                   const __hip_bfloat16* __restrict__ cls,
                   float* __restrict__ s_buf, int b0) {
    int tid = threadIdx.x;
    int wave = tid >> 6, lane = tid & 63;
    int bc = blockIdx.y;
    int f0 = blockIdx.x * 8 + wave * 2;     // 85 blocks cover 680 >= 676
    int fa = f0 < F_ ? f0 : F_ - 1;
    int fb = (f0 + 1) < F_ ? f0 + 1 : F_ - 1;
    union U { float4 f4; __hip_bfloat16 h[8]; };
    const float4* va = (const float4*)(v_buf + ((size_t)(bc * F_ + fa)) * DT_ + lane * 16);
    const float4* vb = (const float4*)(v_buf + ((size_t)(bc * F_ + fb)) * DT_ + lane * 16);
    U a0, a1, b0u, b1u;
    a0.f4 = va[0]; a1.f4 = va[1];
    b0u.f4 = vb[0]; b1u.f4 = vb[1];
    float av[16], bv[16];
    #pragma unroll
    for (int i = 0; i < 8; ++i) {
        av[i] = (float)a0.h[i]; av[8 + i] = (float)a1.h[i];
        bv[i] = (float)b0u.h[i]; bv[8 + i] = (float)b1u.h[i];
    }
    const __hip_bfloat16* cp = cls + ((size_t)(b0 + bc) * K_) * DT_ + lane * 16;
    #pragma unroll
    for (int k = 0; k < K_; ++k) {
        const float4* c4 = (const float4*)(cp + (size_t)k * DT_);
        U c0u, c1u; c0u.f4 = c4[0]; c1u.f4 = c4[1];
        float da = 0.f, db = 0.f;
        #pragma unroll
        for (int i = 0; i < 8; ++i) {
            float cl0 = (float)c0u.h[i], cl1 = (float)c1u.h[i];
            da += av[i] * cl0 + av[8 + i] * cl1;
            db += bv[i] * cl0 + bv[8 + i] * cl1;
        }
        #pragma unroll
        for (int off = 32; off > 0; off >>= 1) {
            da += __shfl_down(da, off);
            db += __shfl_down(db, off);
        }
        if (lane == 0) {
            if (f0 < F_)     s_buf[((size_t)(bc * F_) + f0) * K_ + k] = da;
            if (f0 + 1 < F_) s_buf[((size_t)(bc * F_) + f0 + 1) * K_ + k] = db;
        }
    }
}

// ---------------------------------------------------------------------------
// 5. softmax stats per (bc,k): m = max_f s, rl = 1/sum_f exp(s-m)
__global__ __launch_bounds__(64)
void softmax_stats(const float* __restrict__ s_buf, float2* __restrict__ ml,
                   int b0) {
    int k = blockIdx.x, bc = blockIdx.y, lane = threadIdx.x;
    const float* sp = s_buf + (size_t)bc * F_ * K_ + k;
    float m = -INFINITY;
    for (int f = lane; f < F_; f += 64) m = fmaxf(m, sp[(size_t)f * K_]);
    #pragma unroll
    for (int off = 32; off > 0; off >>= 1) m = fmaxf(m, __shfl_xor(m, off));
    float l = 0.f;
    for (int f = lane; f < F_; f += 64) l += __expf(sp[(size_t)f * K_] - m);
    #pragma unroll
    for (int off = 32; off > 0; off >>= 1) l += __shfl_xor(l, off);
    if (lane == 0) ml[(size_t)(b0 + bc) * K_ + k] = make_float2(m, 1.f / l);
}

// ---------------------------------------------------------------------------
// 6a. partial bap over f-segment, softmax weights computed inline:
//     pp[seg][b][d] = sum_k cls[b,k,d] * sum_{f in seg} w[f,k]*v[bc,f,d]
__global__ __launch_bounds__(256)
void o_bap_partial(const __hip_bfloat16* __restrict__ v_buf,
                   const float* __restrict__ s_buf,
                   const float2* __restrict__ ml,
                   const __hip_bfloat16* __restrict__ cls,
                   float* __restrict__ pp, int b0) {
    int bc = blockIdx.x, seg = blockIdx.y;
    int b = b0 + bc;
    int t = threadIdx.x;
    int f0 = seg * FSEG;
    __shared__ float wbuf[FSEG * K_];          // 520 floats
    __shared__ float mk[K_], rlk[K_];
    __shared__ float red[128 * 8];             // half-1 partial outputs
    if (t < K_) {
        float2 v = ml[(size_t)b * K_ + t];
        mk[t] = v.x; rlk[t] = v.y;
    }
    __syncthreads();
    for (int j = t; j < FSEG * K_; j += 256) {
        int k = j % K_;
        float sv = s_buf[((size_t)bc * F_ + f0) * K_ + j];
        wbuf[j] = __expf(sv - mk[k]) * rlk[k];
    }
    __syncthreads();
    int th = t & 127, half = t >> 7;
    int d0 = th * 8;
    int fs = half * (FSEG / 2);                // 0 or 26
    float acc[K_][8] = {};
    const __hip_bfloat16* vp = v_buf + ((size_t)bc * F_ + f0 + fs) * DT_ + d0;
    for (int f = 0; f < FSEG / 2; ++f) {
        union { float4 f4; __hip_bfloat16 h[8]; } u;
        u.f4 = *(const float4*)(vp + (size_t)f * DT_);
        float vv[8];
        #pragma unroll
        for (int i = 0; i < 8; ++i) vv[i] = (float)u.h[i];
        const float* wk = &wbuf[(fs + f) * K_];
        #pragma unroll
        for (int k = 0; k < K_; ++k)
            #pragma unroll
            for (int i = 0; i < 8; ++i) acc[k][i] += wk[k] * vv[i];
    }
    float outv[8] = {};
    union { float4 f4; __hip_bfloat16 h[8]; } cu;
    #pragma unroll
    for (int k = 0; k < K_; ++k) {
        cu.f4 = *(const float4*)(cls + ((size_t)b * K_ + k) * DT_ + d0);
        #pragma unroll
        for (int i = 0; i < 8; ++i) outv[i] += acc[k][i] * (float)cu.h[i];
    }
    if (half == 1) {
        *(float4*)&red[th * 8]     = *(float4*)&outv[0];
        *(float4*)&red[th * 8 + 4] = *(float4*)&outv[4];
    }
    __syncthreads();
    if (half == 0) {
        #pragma unroll
        for (int i = 0; i < 8; ++i) outv[i] += red[th * 8 + i];
        float* pd = pp + ((size_t)seg * B_ + b) * DT_ + d0;
        *(float4*)pd       = *(float4*)&outv[0];
        *(float4*)(pd + 4) = *(float4*)&outv[4];
    }
}

// 6b. combine segments -> bf16 bap
__global__ void bap_combine(const float* __restrict__ pp,
                            __hip_bfloat16* __restrict__ bap) {
    int idx = blockIdx.x * 256 + threadIdx.x;   // B_*DT_ total
    float s = 0.f;
    #pragma unroll
    for (int g = 0; g < NSEG; ++g) s += pp[idx + (size_t)g * B_ * DT_];
    bap[idx] = (__hip_bfloat16)s;
}

// ---------------------------------------------------------------------------
// 7. lg[b,k] = y[b,:] @ W_fc[:,k] + b_fc[k]; scatter into out
__global__ void final_kernel(const float* __restrict__ y,
                             const float* __restrict__ Wfc,
                             const float* __restrict__ bfc,
                             const int* __restrict__ topk_idx,
                             float* __restrict__ out) {
    int b = blockIdx.x, tid = threadIdx.x;
    int lane = tid & 63, wave = tid >> 6;
    float pk[K_] = {};
    for (int d = tid; d < DT_; d += 256) {
        float yv = y[(size_t)b * DT_ + d];
        #pragma unroll
        for (int k = 0; k < K_; ++k) pk[k] += yv * Wfc[(size_t)d * K_ + k];
    }
    __shared__ float wsum[4][K_];
    #pragma unroll
    for (int k = 0; k < K_; ++k) {
        float a = pk[k];
        #pragma unroll
        for (int off = 32; off > 0; off >>= 1) a += __shfl_down(a, off);
        if (lane == 0) wsum[wave][k] = a;
    }
    __syncthreads();
    if (tid < K_) {
        float lg = wsum[0][tid] + wsum[1][tid] + wsum[2][tid] + wsum[3][tid] + bfc[tid];
        out[(size_t)b * C_ + topk_idx[b * K_ + tid]] = lg;
    }
}

// ---------------------------------------------------------------------------
extern "C" void kernel_launch(void* const* d_in, const int* in_sizes, int n_in,
                              void* d_out, int out_size, void* d_ws, size_t ws_size,
                              hipStream_t stream) {
    const float* ftm           = (const float*)d_in[0];
    const float* logits        = (const float*)d_in[1];
    const int*   indices_table = (const int*)d_in[3];
    const float* word2vec      = (const float*)d_in[4];
    const float* W_emb         = (const float*)d_in[5];
    const float* b_emb         = (const float*)d_in[6];
    const float* W_cls         = (const float*)d_in[7];
    const float* b_cls         = (const float*)d_in[8];
    const float* W_v           = (const float*)d_in[9];
    const float* b_v           = (const float*)d_in[10];
    const float* W_bap         = (const float*)d_in[11];
    const float* b_bap         = (const float*)d_in[12];
    const float* W_fc          = (const float*)d_in[13];
    const float* b_fc          = (const float*)d_in[14];
    float* out = (float*)d_out;

    char* ws = (char*)d_ws;
    size_t off = 0;
    auto alloc = [&](size_t bytes) -> void* {
        void* p = ws + off;
        off = (off + bytes + 255) & ~(size_t)255;
        return p;
    };
    int*            topk_idx = (int*)           alloc((size_t)B_ * K_ * 4);
    __hip_bfloat16* emb_bf   = (__hip_bfloat16*)alloc((size_t)B_ * K_ * DWP_ * 2);
    __hip_bfloat16* cls1     = (__hip_bfloat16*)alloc((size_t)B_ * K_ * DT_ * 2);
    __hip_bfloat16* cls2     = (__hip_bfloat16*)alloc((size_t)B_ * K_ * DT_ * 2);
    __hip_bfloat16* Wemb_t   = (__hip_bfloat16*)alloc((size_t)DT_ * DWP_ * 2);
    __hip_bfloat16* Wcls_t   = (__hip_bfloat16*)alloc((size_t)DT_ * DT_ * 2);
    __hip_bfloat16* Wv_t     = (__hip_bfloat16*)alloc((size_t)DT_ * DF_ * 2);
    __hip_bfloat16* Wbap_t   = (__hip_bfloat16*)alloc((size_t)DT_ * DT_ * 2);
    float*          s_buf    = (float*)         alloc((size_t)B_ * F_ * K_ * 4);
    float2*         ml       = (float2*)        alloc((size_t)B_ * K_ * 8);
    float*          pp       = (float*)         alloc((size_t)NSEG * B_ * DT_ * 4);
    __hip_bfloat16* bap_bf   = (__hip_bfloat16*)alloc((size_t)B_ * DT_ * 2);
    float*          yb       = (float*)         alloc((size_t)B_ * DT_ * 4);

    // dynamic batch-chunk: fit ftm_t + v for nb batches in remaining ws
    size_t per_b = (size_t)F_ * DF_ * 2 + (size_t)F_ * DT_ * 2;
    size_t avail = (ws_size > off + 8192) ? ws_size - off - 8192 : 0;
    int nb = (int)(avail / per_b);
    if (nb > B_) nb = B_;
    if (nb < 1) nb = 1;
    __hip_bfloat16* ftm_t = (__hip_bfloat16*)alloc((size_t)nb * F_ * DF_ * 2);
    __hip_bfloat16* v_buf = (__hip_bfloat16*)alloc((size_t)nb * F_ * DT_ * 2);

    hipMemsetAsync(d_out, 0, (size_t)out_size * sizeof(float), stream);

    topk_kernel<<<B_, 256, 0, stream>>>(logits, topk_idx);
    emb_kernel<<<(B_ * K_ * DWP_ + 255) / 256, 256, 0, stream>>>(
        topk_idx, indices_table, word2vec, emb_bf);

    transpose_weights<<<784, 256, 0, stream>>>(
        W_emb, Wemb_t, W_cls, Wcls_t, W_v, Wv_t, W_bap, Wbap_t);

    // cls path (MFMA, n-fastest grid)
    gemm_mfma<1, 1><<<dim3(DT_ / 128, (B_ * K_ + 127) / 128), 256, 0, stream>>>(
        emb_bf, Wemb_t, b_emb, cls1, B_ * K_, DT_, DWP_);
    gemm_mfma<1, 1><<<dim3(DT_ / 128, (B_ * K_ + 127) / 128), 256, 0, stream>>>(
        cls1, Wcls_t, b_cls, cls2, B_ * K_, DT_, DT_);

    // main path, chunked only if ws is small (nb == 64 -> single pass)
    for (int b0 = 0; b0 < B_; b0 += nb) {
        int cb = min(nb, B_ - b0);
        transpose_ftm<<<dim3((F_ + 63) / 64, DF_ / 64, cb), 256, 0, stream>>>(
            ftm + (size_t)b0 * DF_ * F_, ftm_t);
        int M = cb * F_;
        if ((M & 255) == 0) {
            gemm_mfma256<<<dim3(DT_ / 256, M / 256), 512, 0, stream>>>(
                ftm_t, Wv_t, b_v, v_buf, M, DT_, DF_);
        } else {
            gemm_mfma<1, 1><<<dim3(DT_ / 128, (M + 127) / 128), 256, 0, stream>>>(
                ftm_t, Wv_t, b_v, v_buf, M, DT_, DF_);
        }
        float* s_c = s_buf + (size_t)b0 * F_ * K_;
        attn_s_kernel<<<dim3((F_ + 7) / 8, cb), 256, 0, stream>>>(
            v_buf, cls2, s_c, b0);
        softmax_stats<<<dim3(K_, cb), 64, 0, stream>>>(s_c, ml, b0);
        o_bap_partial<<<dim3(cb, NSEG), 256, 0, stream>>>(
            v_buf, s_c, ml, cls2, pp, b0);
    }
    bap_combine<<<B_ * DT_ / 256, 256, 0, stream>>>(pp, bap_bf);

    gemm_mfma<1, 0><<<dim3(DT_ / 128, 1), 256, 0, stream>>>(
        bap_bf, Wbap_t, b_bap, yb, B_, DT_, DT_);
    final_kernel<<<B_, 256, 0, stream>>>(yb, W_fc, b_fc, topk_idx, out);
}

// Round 3
// 486.421 us; speedup vs baseline: 1.0011x; 1.0011x over previous
//
#include <hip/hip_runtime.h>
#include <hip/hip_bf16.h>

// Problem constants
#define B_   64
#define C_   3129
#define K_   10
#define DF_  768
#define F_   676      // 26*26
#define DW_  300
#define DWP_ 320      // DW_ padded to multiple of 64 (MFMA K-tile)
#define DT_  1024
#define NSEG 13       // o_bap f-segments: 676 = 13*52 (832 blocks -> 3.25/CU)
#define FSEG 52

typedef __attribute__((ext_vector_type(8))) short short8;   // 8 bf16
typedef __attribute__((ext_vector_type(4))) float floatx4;  // 4 fp32

// async 16B global -> LDS (wave-uniform LDS base + lane*16)
__device__ __forceinline__ void gload_lds16(const void* g, void* l) {
    __builtin_amdgcn_global_load_lds(
        (const __attribute__((address_space(1))) void*)g,
        (__attribute__((address_space(3))) void*)l, 16, 0, 0);
}

// ---------------------------------------------------------------------------
// 1. fused top-k (K=10, exact lax.top_k order) + class embedding for the
//    same b (topk[b] only feeds emb[b] -> same block, no cross-block dep).
__global__ void topk_emb_kernel(const float* __restrict__ logits,
                                const int* __restrict__ indices_table,
                                const float* __restrict__ word2vec,
                                int* __restrict__ topk_idx,
                                __hip_bfloat16* __restrict__ emb) {
    __shared__ float vals[C_];
    __shared__ float red_v[256];
    __shared__ int   red_i[256];
    __shared__ int   sel[K_];
    int b = blockIdx.x;
    int tid = threadIdx.x;
    for (int i = tid; i < C_; i += 256) vals[i] = logits[(size_t)b * C_ + i];
    __syncthreads();
    for (int s = 0; s < K_; ++s) {
        float bv = -INFINITY; int bi = 0x7fffffff;
        for (int i = tid; i < C_; i += 256) {
            float v = vals[i];
            if (v > bv) { bv = v; bi = i; }
        }
        red_v[tid] = bv; red_i[tid] = bi;
        __syncthreads();
        for (int st = 128; st > 0; st >>= 1) {
            if (tid < st) {
                float ov = red_v[tid + st]; int oi = red_i[tid + st];
                if (ov > red_v[tid] || (ov == red_v[tid] && oi < red_i[tid])) {
                    red_v[tid] = ov; red_i[tid] = oi;
                }
            }
            __syncthreads();
        }
        if (tid == 0) {
            sel[s] = red_i[0];
            topk_idx[b * K_ + s] = red_i[0];
            vals[red_i[0]] = -INFINITY;
        }
        __syncthreads();
    }
    // emb: 10 x DWP_ bf16 values for this b (zero-padded j >= DW_)
    for (int idx = tid; idx < K_ * DWP_; idx += 256) {
        int j  = idx % DWP_;
        int kk = idx / DWP_;
        float s = 0.f;
        if (j < DW_) {
            const int* tbl = indices_table + (size_t)sel[kk] * 4;
            #pragma unroll
            for (int i = 0; i < 4; ++i) s += word2vec[(size_t)tbl[i] * DW_ + j];
            s *= 0.25f;
        }
        emb[((size_t)b * K_ + kk) * DWP_ + j] = (__hip_bfloat16)s;
    }
}

// ---------------------------------------------------------------------------
// Transpose body: src[R][Cc] fp32 -> dst[Cc][Rp] bf16, zero-padded rows >= R.
__device__ __forceinline__ void tp_body(const float* __restrict__ s,
                                        __hip_bfloat16* __restrict__ d,
                                        int R, int Cc, int Rp, int c0, int r0) {
    __shared__ float tile[64][65];
    int t = threadIdx.x;
    int cl = (t & 15) * 4;
    int rl = t >> 4;
    #pragma unroll
    for (int i = 0; i < 4; ++i) {
        int r = rl + i * 16;
        float4 v = make_float4(0.f, 0.f, 0.f, 0.f);
        if (r0 + r < R && c0 + cl < Cc)
            v = *(const float4*)(s + (size_t)(r0 + r) * Cc + c0 + cl);
        tile[r][cl + 0] = v.x; tile[r][cl + 1] = v.y;
        tile[r][cl + 2] = v.z; tile[r][cl + 3] = v.w;
    }
    __syncthreads();
    int cw = t >> 2;
    int r4 = (t & 3) * 16;
    if (c0 + cw < Cc) {
        __align__(16) __hip_bfloat16 buf[16];
        #pragma unroll
        for (int j = 0; j < 16; ++j) buf[j] = (__hip_bfloat16)tile[r4 + j][cw];
        float4* dp = (float4*)(d + (size_t)(c0 + cw) * Rp + r0 + r4);
        dp[0] = *(float4*)&buf[0];
        dp[1] = *(float4*)&buf[8];
    }
}

// ftm transpose (z-batched) -- fallback path for chunked (small ws) mode
__global__ __launch_bounds__(256)
void transpose_ftm(const float* __restrict__ src, __hip_bfloat16* __restrict__ dst) {
    tp_body(src + (size_t)blockIdx.z * DF_ * F_,
            dst + (size_t)blockIdx.z * F_ * DF_,
            DF_, F_, DF_, blockIdx.x * 64, blockIdx.y * 64);
}

// weight transposes only -- fallback path
__global__ __launch_bounds__(256)
void transpose_weights(const float* __restrict__ Wemb, __hip_bfloat16* __restrict__ WembT,
                       const float* __restrict__ Wcls, __hip_bfloat16* __restrict__ WclsT,
                       const float* __restrict__ Wv,   __hip_bfloat16* __restrict__ WvT,
                       const float* __restrict__ Wbap, __hip_bfloat16* __restrict__ WbapT) {
    int id = blockIdx.x;
    const float* s; __hip_bfloat16* d; int R, Rp;
    if (id < 80)       { s = Wemb; d = WembT; R = DW_;  Rp = DWP_; }
    else if (id < 336) { s = Wcls; d = WclsT; R = DT_;  Rp = DT_;  id -= 80;  }
    else if (id < 528) { s = Wv;   d = WvT;   R = DF_;  Rp = DF_;  id -= 336; }
    else               { s = Wbap; d = WbapT; R = DT_;  Rp = DT_;  id -= 528; }
    int bx = id & 15;        // Cc = 1024 -> 16 col tiles for all mats
    int by = id >> 4;
    tp_body(s, d, R, DT_, Rp, bx * 64, by * 64);
}

// all 4 weight transposes + full ftm transpose in ONE dispatch.
// ids: [0,784) weights (as transpose_weights); [784, 784+8448) ftm tiles
// (z = id/132, tile = id%132, bx = tile%11, by = tile/11).
__global__ __launch_bounds__(256)
void transpose_all(const float* __restrict__ Wemb, __hip_bfloat16* __restrict__ WembT,
                   const float* __restrict__ Wcls, __hip_bfloat16* __restrict__ WclsT,
                   const float* __restrict__ Wv,   __hip_bfloat16* __restrict__ WvT,
                   const float* __restrict__ Wbap, __hip_bfloat16* __restrict__ WbapT,
                   const float* __restrict__ ftm,  __hip_bfloat16* __restrict__ ftm_t) {
    int id = blockIdx.x;
    if (id >= 784) {
        id -= 784;
        int z = id / 132;
        int t2 = id % 132;
        int bx = t2 % 11, by = t2 / 11;
        tp_body(ftm + (size_t)z * DF_ * F_, ftm_t + (size_t)z * F_ * DF_,
                DF_, F_, DF_, bx * 64, by * 64);
        return;
    }
    const float* s; __hip_bfloat16* d; int R, Rp;
    if (id < 80)       { s = Wemb; d = WembT; R = DW_;  Rp = DWP_; }
    else if (id < 336) { s = Wcls; d = WclsT; R = DT_;  Rp = DT_;  id -= 80;  }
    else if (id < 528) { s = Wv;   d = WvT;   R = DF_;  Rp = DF_;  id -= 336; }
    else               { s = Wbap; d = WbapT; R = DT_;  Rp = DT_;  id -= 528; }
    int bx = id & 15;
    int by = id >> 4;
    tp_body(s, d, R, DT_, Rp, bx * 64, by * 64);
}

// ---------------------------------------------------------------------------
// MFMA bf16 GEMM: C[M][N] = act(A[M][Kp] @ Bt[N][Kp]^T + bias)
// 128x128 tile, BK=64, global_load_lds w16 with XOR chunk swizzle (bank-free
// fragment reads), coalesced LDS epilogue (OUTBF=1), XCD-bijective remap.
template <int RELU, int OUTBF>
__global__ __launch_bounds__(256)
void gemm_mfma(const __hip_bfloat16* __restrict__ A,
               const __hip_bfloat16* __restrict__ Bt,
               const float* __restrict__ bias,
               void* __restrict__ Cout, int M, int N, int Kp) {
    __shared__ __align__(16) char smem[34816];       // max(As+Bs, C-tile 128x136)
    __hip_bfloat16* As = (__hip_bfloat16*)smem;      // [128][64]
    __hip_bfloat16* Bs = As + 128 * 64;              // [128][64]
    int tid = threadIdx.x;
    int wave = tid >> 6, lane = tid & 63;
    int quad = lane >> 4, l16 = lane & 15;
    int wm = (wave & 1) * 64, wn = (wave >> 1) * 64;

    // XCD-aware bijective remap (m204)
    int gx = gridDim.x;
    int nwg = gx * gridDim.y;
    int flat = blockIdx.y * gx + blockIdx.x;
    int q = nwg >> 3, r = nwg & 7;
    int xcd = flat & 7, lid = flat >> 3;
    int o = (xcd < r ? xcd * (q + 1) : r * (q + 1) + (xcd - r) * q) + lid;
    int n0 = (o % gx) * 128;
    int m0 = (o / gx) * 128;

    floatx4 acc[4][4];
    #pragma unroll
    for (int i = 0; i < 4; ++i)
        #pragma unroll
        for (int j = 0; j < 4; ++j)
            acc[i][j] = (floatx4){0.f, 0.f, 0.f, 0.f};

    int rsub = lane >> 3;
    int gchunk = (lane & 7) ^ rsub;

    int arow[4], brow[4];
    #pragma unroll
    for (int i = 0; i < 4; ++i) {
        arow[i] = wm + i * 16 + l16;
        brow[i] = wn + i * 16 + l16;
    }

    for (int k0 = 0; k0 < Kp; k0 += 64) {
        #pragma unroll
        for (int c = 0; c < 4; ++c) {
            int grp = wave * 4 + c;
            int row = grp * 8 + rsub;
            int ra = m0 + row; if (ra >= M) ra = M - 1;   // clamp: junk unused
            gload_lds16(A + (size_t)ra * Kp + k0 + gchunk * 8, As + grp * 512);
            gload_lds16(Bt + (size_t)(n0 + row) * Kp + k0 + gchunk * 8, Bs + grp * 512);
        }
        __syncthreads();
        #pragma unroll
        for (int ks = 0; ks < 2; ++ks) {
            short8 af[4], bf[4];
            #pragma unroll
            for (int mi = 0; mi < 4; ++mi)
                af[mi] = *(const short8*)&As[arow[mi] * 64 +
                            ((((ks << 2) | quad) ^ (arow[mi] & 7)) << 3)];
            #pragma unroll
            for (int ni = 0; ni < 4; ++ni)
                bf[ni] = *(const short8*)&Bs[brow[ni] * 64 +
                            ((((ks << 2) | quad) ^ (brow[ni] & 7)) << 3)];
            #pragma unroll
            for (int mi = 0; mi < 4; ++mi)
                #pragma unroll
                for (int ni = 0; ni < 4; ++ni)
                    acc[mi][ni] = __builtin_amdgcn_mfma_f32_16x16x32_bf16(
                        af[mi], bf[ni], acc[mi][ni], 0, 0, 0);
        }
        __syncthreads();
    }

    // C/D mapping: col = lane&15, row = quad*4 + reg  [measured m89/m91]
    float bn[4];
    #pragma unroll
    for (int ni = 0; ni < 4; ++ni) bn[ni] = bias[n0 + wn + ni * 16 + l16];

    if (OUTBF) {
        __hip_bfloat16* Cs = (__hip_bfloat16*)smem;
        #pragma unroll
        for (int mi = 0; mi < 4; ++mi)
            #pragma unroll
            for (int rr = 0; rr < 4; ++rr) {
                int row = wm + mi * 16 + quad * 4 + rr;
                #pragma unroll
                for (int ni = 0; ni < 4; ++ni) {
                    float val = acc[mi][ni][rr] + bn[ni];
                    if (RELU) val = fmaxf(val, 0.f);
                    Cs[row * 136 + wn + ni * 16 + l16] = (__hip_bfloat16)val;
                }
            }
        __syncthreads();
        #pragma unroll
        for (int j = 0; j < 8; ++j) {
            int ch = tid + 256 * j;              // 2048 chunks of 16 B
            int row = ch >> 4, c16 = ch & 15;
            int r = m0 + row;
            float4 val = *(const float4*)&Cs[row * 136 + c16 * 8];
            if (r < M)
                *(float4*)((__hip_bfloat16*)Cout + (size_t)r * N + n0 + c16 * 8) = val;
        }
    } else {
        #pragma unroll
        for (int mi = 0; mi < 4; ++mi)
            #pragma unroll
            for (int rr = 0; rr < 4; ++rr) {
                int r = m0 + wm + mi * 16 + quad * 4 + rr;
                if (r < M) {
                    #pragma unroll
                    for (int ni = 0; ni < 4; ++ni) {
                        float val = acc[mi][ni][rr] + bn[ni];
                        if (RELU) val = fmaxf(val, 0.f);
                        ((float*)Cout)[(size_t)r * N + n0 + wn + ni * 16 + l16] = val;
                    }
                }
            }
    }
}

// ---------------------------------------------------------------------------
// 4. s[bc,f,k] = sum_d v[bc,f,d] * cls[b0+bc,k,d]; 2 f per wave (halves cls
//    L2 traffic).
__global__ __launch_bounds__(256)
void attn_s_kernel(const __hip_bfloat16* __restrict__ v_buf,
                   const __hip_bfloat16* __restrict__ cls,
                   float* __restrict__ s_buf, int b0) {
    int tid = threadIdx.x;
    int wave = tid >> 6, lane = tid & 63;
    int bc = blockIdx.y;
    int f0 = blockIdx.x * 8 + wave * 2;     // 85 blocks cover 680 >= 676
    int fa = f0 < F_ ? f0 : F_ - 1;
    int fb = (f0 + 1) < F_ ? f0 + 1 : F_ - 1;
    union U { float4 f4; __hip_bfloat16 h[8]; };
    const float4* va = (const float4*)(v_buf + ((size_t)(bc * F_ + fa)) * DT_ + lane * 16);
    const float4* vb = (const float4*)(v_buf + ((size_t)(bc * F_ + fb)) * DT_ + lane * 16);
    U a0, a1, b0u, b1u;
    a0.f4 = va[0]; a1.f4 = va[1];
    b0u.f4 = vb[0]; b1u.f4 = vb[1];
    float av[16], bv[16];
    #pragma unroll
    for (int i = 0; i < 8; ++i) {
        av[i] = (float)a0.h[i]; av[8 + i] = (float)a1.h[i];
        bv[i] = (float)b0u.h[i]; bv[8 + i] = (float)b1u.h[i];
    }
    const __hip_bfloat16* cp = cls + ((size_t)(b0 + bc) * K_) * DT_ + lane * 16;
    #pragma unroll
    for (int k = 0; k < K_; ++k) {
        const float4* c4 = (const float4*)(cp + (size_t)k * DT_);
        U c0u, c1u; c0u.f4 = c4[0]; c1u.f4 = c4[1];
        float da = 0.f, db = 0.f;
        #pragma unroll
        for (int i = 0; i < 8; ++i) {
            float cl0 = (float)c0u.h[i], cl1 = (float)c1u.h[i];
            da += av[i] * cl0 + av[8 + i] * cl1;
            db += bv[i] * cl0 + bv[8 + i] * cl1;
        }
        #pragma unroll
        for (int off = 32; off > 0; off >>= 1) {
            da += __shfl_down(da, off);
            db += __shfl_down(db, off);
        }
        if (lane == 0) {
            if (f0 < F_)     s_buf[((size_t)(bc * F_) + f0) * K_ + k] = da;
            if (f0 + 1 < F_) s_buf[((size_t)(bc * F_) + f0 + 1) * K_ + k] = db;
        }
    }
}

// ---------------------------------------------------------------------------
// 6a. partial bap over f-segment; softmax stats AND weights computed inline
//     (stats recomputed per block from L2-resident s_buf -- removes the
//     softmax_stats dispatch):
//     pp[seg][b][d] = sum_k cls[b,k,d] * sum_{f in seg} w[f,k]*v[bc,f,d]
__global__ __launch_bounds__(256)
void o_bap_partial(const __hip_bfloat16* __restrict__ v_buf,
                   const float* __restrict__ s_buf,
                   const __hip_bfloat16* __restrict__ cls,
                   float* __restrict__ pp, int b0) {
    int bc = blockIdx.x, seg = blockIdx.y;
    int b = b0 + bc;
    int t = threadIdx.x;
    int f0 = seg * FSEG;
    __shared__ float wbuf[FSEG * K_];          // 520 floats
    __shared__ float mk[K_], rlk[K_];
    __shared__ float red[128 * 8];             // half-1 partial outputs

    // stats: 16 lanes per k (k = t>>4 for t<160), strided column scan,
    // 16-wide shfl reduction (lane groups stay inside one wave).
    if (t < 16 * K_) {
        int k = t >> 4, fi = t & 15;
        const float* sp = s_buf + (size_t)bc * F_ * K_ + k;
        float m = -INFINITY;
        for (int f = fi; f < F_; f += 16) m = fmaxf(m, sp[(size_t)f * K_]);
        #pragma unroll
        for (int off = 8; off > 0; off >>= 1) m = fmaxf(m, __shfl_xor(m, off, 16));
        float l = 0.f;
        for (int f = fi; f < F_; f += 16) l += __expf(sp[(size_t)f * K_] - m);
        #pragma unroll
        for (int off = 8; off > 0; off >>= 1) l += __shfl_xor(l, off, 16);
        if (fi == 0) { mk[k] = m; rlk[k] = 1.f / l; }
    }
    __syncthreads();
    for (int j = t; j < FSEG * K_; j += 256) {
        int k = j % K_;
        float sv = s_buf[((size_t)bc * F_ + f0) * K_ + j];
        wbuf[j] = __expf(sv - mk[k]) * rlk[k];
    }
    __syncthreads();
    int th = t & 127, half = t >> 7;
    int d0 = th * 8;
    int fs = half * (FSEG / 2);                // 0 or 26
    float acc[K_][8] = {};
    const __hip_bfloat16* vp = v_buf + ((size_t)bc * F_ + f0 + fs) * DT_ + d0;
    for (int f = 0; f < FSEG / 2; ++f) {
        union { float4 f4; __hip_bfloat16 h[8]; } u;
        u.f4 = *(const float4*)(vp + (size_t)f * DT_);
        float vv[8];
        #pragma unroll
        for (int i = 0; i < 8; ++i) vv[i] = (float)u.h[i];
        const float* wk = &wbuf[(fs + f) * K_];
        #pragma unroll
        for (int k = 0; k < K_; ++k)
            #pragma unroll
            for (int i = 0; i < 8; ++i) acc[k][i] += wk[k] * vv[i];
    }
    float outv[8] = {};
    union { float4 f4; __hip_bfloat16 h[8]; } cu;
    #pragma unroll
    for (int k = 0; k < K_; ++k) {
        cu.f4 = *(const float4*)(cls + ((size_t)b * K_ + k) * DT_ + d0);
        #pragma unroll
        for (int i = 0; i < 8; ++i) outv[i] += acc[k][i] * (float)cu.h[i];
    }
    if (half == 1) {
        *(float4*)&red[th * 8]     = *(float4*)&outv[0];
        *(float4*)&red[th * 8 + 4] = *(float4*)&outv[4];
    }
    __syncthreads();
    if (half == 0) {
        #pragma unroll
        for (int i = 0; i < 8; ++i) outv[i] += red[th * 8 + i];
        float* pd = pp + ((size_t)seg * B_ + b) * DT_ + d0;
        *(float4*)pd       = *(float4*)&outv[0];
        *(float4*)(pd + 4) = *(float4*)&outv[4];
    }
}

// 6b. combine segments -> bf16 bap
__global__ void bap_combine(const float* __restrict__ pp,
                            __hip_bfloat16* __restrict__ bap) {
    int idx = blockIdx.x * 256 + threadIdx.x;   // B_*DT_ total
    float s = 0.f;
    #pragma unroll
    for (int g = 0; g < NSEG; ++g) s += pp[idx + (size_t)g * B_ * DT_];
    bap[idx] = (__hip_bfloat16)s;
}

// ---------------------------------------------------------------------------
// 7. lg[b,k] = y[b,:] @ W_fc[:,k] + b_fc[k]; scatter into out
__global__ void final_kernel(const float* __restrict__ y,
                             const float* __restrict__ Wfc,
                             const float* __restrict__ bfc,
                             const int* __restrict__ topk_idx,
                             float* __restrict__ out) {
    int b = blockIdx.x, tid = threadIdx.x;
    int lane = tid & 63, wave = tid >> 6;
    float pk[K_] = {};
    for (int d = tid; d < DT_; d += 256) {
        float yv = y[(size_t)b * DT_ + d];
        #pragma unroll
        for (int k = 0; k < K_; ++k) pk[k] += yv * Wfc[(size_t)d * K_ + k];
    }
    __shared__ float wsum[4][K_];
    #pragma unroll
    for (int k = 0; k < K_; ++k) {
        float a = pk[k];
        #pragma unroll
        for (int off = 32; off > 0; off >>= 1) a += __shfl_down(a, off);
        if (lane == 0) wsum[wave][k] = a;
    }
    __syncthreads();
    if (tid < K_) {
        float lg = wsum[0][tid] + wsum[1][tid] + wsum[2][tid] + wsum[3][tid] + bfc[tid];
        out[(size_t)b * C_ + topk_idx[b * K_ + tid]] = lg;
    }
}

// ---------------------------------------------------------------------------
extern "C" void kernel_launch(void* const* d_in, const int* in_sizes, int n_in,
                              void* d_out, int out_size, void* d_ws, size_t ws_size,
                              hipStream_t stream) {
    const float* ftm           = (const float*)d_in[0];
    const float* logits        = (const float*)d_in[1];
    const int*   indices_table = (const int*)d_in[3];
    const float* word2vec      = (const float*)d_in[4];
    const float* W_emb         = (const float*)d_in[5];
    const float* b_emb         = (const float*)d_in[6];
    const float* W_cls         = (const float*)d_in[7];
    const float* b_cls         = (const float*)d_in[8];
    const float* W_v           = (const float*)d_in[9];
    const float* b_v           = (const float*)d_in[10];
    const float* W_bap         = (const float*)d_in[11];
    const float* b_bap         = (const float*)d_in[12];
    const float* W_fc          = (const float*)d_in[13];
    const float* b_fc          = (const float*)d_in[14];
    float* out = (float*)d_out;

    char* ws = (char*)d_ws;
    size_t off = 0;
    auto alloc = [&](size_t bytes) -> void* {
        void* p = ws + off;
        off = (off + bytes + 255) & ~(size_t)255;
        return p;
    };
    int*            topk_idx = (int*)           alloc((size_t)B_ * K_ * 4);
    __hip_bfloat16* emb_bf   = (__hip_bfloat16*)alloc((size_t)B_ * K_ * DWP_ * 2);
    __hip_bfloat16* cls1     = (__hip_bfloat16*)alloc((size_t)B_ * K_ * DT_ * 2);
    __hip_bfloat16* cls2     = (__hip_bfloat16*)alloc((size_t)B_ * K_ * DT_ * 2);
    __hip_bfloat16* Wemb_t   = (__hip_bfloat16*)alloc((size_t)DT_ * DWP_ * 2);
    __hip_bfloat16* Wcls_t   = (__hip_bfloat16*)alloc((size_t)DT_ * DT_ * 2);
    __hip_bfloat16* Wv_t     = (__hip_bfloat16*)alloc((size_t)DT_ * DF_ * 2);
    __hip_bfloat16* Wbap_t   = (__hip_bfloat16*)alloc((size_t)DT_ * DT_ * 2);
    float*          s_buf    = (float*)         alloc((size_t)B_ * F_ * K_ * 4);
    float*          pp       = (float*)         alloc((size_t)NSEG * B_ * DT_ * 4);
    __hip_bfloat16* bap_bf   = (__hip_bfloat16*)alloc((size_t)B_ * DT_ * 2);
    float*          yb       = (float*)         alloc((size_t)B_ * DT_ * 4);

    // dynamic batch-chunk: fit ftm_t + v for nb batches in remaining ws
    size_t per_b = (size_t)F_ * DF_ * 2 + (size_t)F_ * DT_ * 2;
    size_t avail = (ws_size > off + 8192) ? ws_size - off - 8192 : 0;
    int nb = (int)(avail / per_b);
    if (nb > B_) nb = B_;
    if (nb < 1) nb = 1;
    __hip_bfloat16* ftm_t = (__hip_bfloat16*)alloc((size_t)nb * F_ * DF_ * 2);
    __hip_bfloat16* v_buf = (__hip_bfloat16*)alloc((size_t)nb * F_ * DT_ * 2);

    hipMemsetAsync(d_out, 0, (size_t)out_size * sizeof(float), stream);

    topk_emb_kernel<<<B_, 256, 0, stream>>>(logits, indices_table, word2vec,
                                            topk_idx, emb_bf);

    if (nb == B_) {
        // all transposes (weights + full ftm) in one dispatch
        transpose_all<<<784 + 132 * B_, 256, 0, stream>>>(
            W_emb, Wemb_t, W_cls, Wcls_t, W_v, Wv_t, W_bap, Wbap_t, ftm, ftm_t);
    } else {
        transpose_weights<<<784, 256, 0, stream>>>(
            W_emb, Wemb_t, W_cls, Wcls_t, W_v, Wv_t, W_bap, Wbap_t);
    }

    // cls path (MFMA, n-fastest grid)
    gemm_mfma<1, 1><<<dim3(DT_ / 128, (B_ * K_ + 127) / 128), 256, 0, stream>>>(
        emb_bf, Wemb_t, b_emb, cls1, B_ * K_, DT_, DWP_);
    gemm_mfma<1, 1><<<dim3(DT_ / 128, (B_ * K_ + 127) / 128), 256, 0, stream>>>(
        cls1, Wcls_t, b_cls, cls2, B_ * K_, DT_, DT_);

    // main path, chunked only if ws is small (nb == 64 -> single pass)
    for (int b0 = 0; b0 < B_; b0 += nb) {
        int cb = min(nb, B_ - b0);
        if (nb != B_) {
            transpose_ftm<<<dim3((F_ + 63) / 64, DF_ / 64, cb), 256, 0, stream>>>(
                ftm + (size_t)b0 * DF_ * F_, ftm_t);
        }
        int M = cb * F_;
        gemm_mfma<1, 1><<<dim3(DT_ / 128, (M + 127) / 128), 256, 0, stream>>>(
            ftm_t, Wv_t, b_v, v_buf, M, DT_, DF_);
        float* s_c = s_buf + (size_t)b0 * F_ * K_;
        attn_s_kernel<<<dim3((F_ + 7) / 8, cb), 256, 0, stream>>>(
            v_buf, cls2, s_c, b0);
        o_bap_partial<<<dim3(cb, NSEG), 256, 0, stream>>>(
            v_buf, s_c, cls2, pp, b0);
    }
    bap_combine<<<B_ * DT_ / 256, 256, 0, stream>>>(pp, bap_bf);

    gemm_mfma<1, 0><<<dim3(DT_ / 128, 1), 256, 0, stream>>>(
        bap_bf, Wbap_t, b_bap, yb, B_, DT_, DT_);
    final_kernel<<<B_, 256, 0, stream>>>(yb, W_fc, b_fc, topk_idx, out);
}

// Round 4
// 462.839 us; speedup vs baseline: 1.0521x; 1.0510x over previous
//
#include <hip/hip_runtime.h>
#include <hip/hip_bf16.h>

// Problem constants
#define B_   64
#define C_   3129
#define K_   10
#define DF_  768
#define F_   676      // 26*26
#define DW_  300
#define DWP_ 320      // DW_ padded to multiple of 64 (MFMA K-tile)
#define DT_  1024
#define NSEG 13       // o_bap f-segments: 676 = 13*52 (832 blocks -> 3.25/CU)
#define FSEG 52

typedef __attribute__((ext_vector_type(8))) short short8;   // 8 bf16
typedef __attribute__((ext_vector_type(4))) float floatx4;  // 4 fp32

// async 16B global -> LDS (wave-uniform LDS base + lane*16)
__device__ __forceinline__ void gload_lds16(const void* g, void* l) {
    __builtin_amdgcn_global_load_lds(
        (const __attribute__((address_space(1))) void*)g,
        (__attribute__((address_space(3))) void*)l, 16, 0, 0);
}

// ---------------------------------------------------------------------------
// 1. fused top-k (K=10, exact lax.top_k order) + class embedding for the
//    same b (topk[b] only feeds emb[b] -> same block, no cross-block dep).
__global__ void topk_emb_kernel(const float* __restrict__ logits,
                                const int* __restrict__ indices_table,
                                const float* __restrict__ word2vec,
                                int* __restrict__ topk_idx,
                                __hip_bfloat16* __restrict__ emb) {
    __shared__ float vals[C_];
    __shared__ float red_v[256];
    __shared__ int   red_i[256];
    __shared__ int   sel[K_];
    int b = blockIdx.x;
    int tid = threadIdx.x;
    for (int i = tid; i < C_; i += 256) vals[i] = logits[(size_t)b * C_ + i];
    __syncthreads();
    for (int s = 0; s < K_; ++s) {
        float bv = -INFINITY; int bi = 0x7fffffff;
        for (int i = tid; i < C_; i += 256) {
            float v = vals[i];
            if (v > bv) { bv = v; bi = i; }
        }
        red_v[tid] = bv; red_i[tid] = bi;
        __syncthreads();
        for (int st = 128; st > 0; st >>= 1) {
            if (tid < st) {
                float ov = red_v[tid + st]; int oi = red_i[tid + st];
                if (ov > red_v[tid] || (ov == red_v[tid] && oi < red_i[tid])) {
                    red_v[tid] = ov; red_i[tid] = oi;
                }
            }
            __syncthreads();
        }
        if (tid == 0) {
            sel[s] = red_i[0];
            topk_idx[b * K_ + s] = red_i[0];
            vals[red_i[0]] = -INFINITY;
        }
        __syncthreads();
    }
    // emb: 10 x DWP_ bf16 values for this b (zero-padded j >= DW_)
    for (int idx = tid; idx < K_ * DWP_; idx += 256) {
        int j  = idx % DWP_;
        int kk = idx / DWP_;
        float s = 0.f;
        if (j < DW_) {
            const int* tbl = indices_table + (size_t)sel[kk] * 4;
            #pragma unroll
            for (int i = 0; i < 4; ++i) s += word2vec[(size_t)tbl[i] * DW_ + j];
            s *= 0.25f;
        }
        emb[((size_t)b * K_ + kk) * DWP_ + j] = (__hip_bfloat16)s;
    }
}

// ---------------------------------------------------------------------------
// Transpose body: src[R][Cc] fp32 -> dst[Cc][Rp] bf16, zero-padded rows >= R.
__device__ __forceinline__ void tp_body(const float* __restrict__ s,
                                        __hip_bfloat16* __restrict__ d,
                                        int R, int Cc, int Rp, int c0, int r0) {
    __shared__ float tile[64][65];
    int t = threadIdx.x;
    int cl = (t & 15) * 4;
    int rl = t >> 4;
    #pragma unroll
    for (int i = 0; i < 4; ++i) {
        int r = rl + i * 16;
        float4 v = make_float4(0.f, 0.f, 0.f, 0.f);
        if (r0 + r < R && c0 + cl < Cc)
            v = *(const float4*)(s + (size_t)(r0 + r) * Cc + c0 + cl);
        tile[r][cl + 0] = v.x; tile[r][cl + 1] = v.y;
        tile[r][cl + 2] = v.z; tile[r][cl + 3] = v.w;
    }
    __syncthreads();
    int cw = t >> 2;
    int r4 = (t & 3) * 16;
    if (c0 + cw < Cc) {
        __align__(16) __hip_bfloat16 buf[16];
        #pragma unroll
        for (int j = 0; j < 16; ++j) buf[j] = (__hip_bfloat16)tile[r4 + j][cw];
        float4* dp = (float4*)(d + (size_t)(c0 + cw) * Rp + r0 + r4);
        dp[0] = *(float4*)&buf[0];
        dp[1] = *(float4*)&buf[8];
    }
}

// ftm transpose (z-batched) -- fallback path for chunked (small ws) mode
__global__ __launch_bounds__(256)
void transpose_ftm(const float* __restrict__ src, __hip_bfloat16* __restrict__ dst) {
    tp_body(src + (size_t)blockIdx.z * DF_ * F_,
            dst + (size_t)blockIdx.z * F_ * DF_,
            DF_, F_, DF_, blockIdx.x * 64, blockIdx.y * 64);
}

// weight transposes only -- fallback path
__global__ __launch_bounds__(256)
void transpose_weights(const float* __restrict__ Wemb, __hip_bfloat16* __restrict__ WembT,
                       const float* __restrict__ Wcls, __hip_bfloat16* __restrict__ WclsT,
                       const float* __restrict__ Wv,   __hip_bfloat16* __restrict__ WvT,
                       const float* __restrict__ Wbap, __hip_bfloat16* __restrict__ WbapT) {
    int id = blockIdx.x;
    const float* s; __hip_bfloat16* d; int R, Rp;
    if (id < 80)       { s = Wemb; d = WembT; R = DW_;  Rp = DWP_; }
    else if (id < 336) { s = Wcls; d = WclsT; R = DT_;  Rp = DT_;  id -= 80;  }
    else if (id < 528) { s = Wv;   d = WvT;   R = DF_;  Rp = DF_;  id -= 336; }
    else               { s = Wbap; d = WbapT; R = DT_;  Rp = DT_;  id -= 528; }
    int bx = id & 15;        // Cc = 1024 -> 16 col tiles for all mats
    int by = id >> 4;
    tp_body(s, d, R, DT_, Rp, bx * 64, by * 64);
}

// all 4 weight transposes + full ftm transpose in ONE dispatch.
// ids: [0,784) weights; [784, 784+8448) ftm tiles
__global__ __launch_bounds__(256)
void transpose_all(const float* __restrict__ Wemb, __hip_bfloat16* __restrict__ WembT,
                   const float* __restrict__ Wcls, __hip_bfloat16* __restrict__ WclsT,
                   const float* __restrict__ Wv,   __hip_bfloat16* __restrict__ WvT,
                   const float* __restrict__ Wbap, __hip_bfloat16* __restrict__ WbapT,
                   const float* __restrict__ ftm,  __hip_bfloat16* __restrict__ ftm_t) {
    int id = blockIdx.x;
    if (id >= 784) {
        id -= 784;
        int z = id / 132;
        int t2 = id % 132;
        int bx = t2 % 11, by = t2 / 11;
        tp_body(ftm + (size_t)z * DF_ * F_, ftm_t + (size_t)z * F_ * DF_,
                DF_, F_, DF_, bx * 64, by * 64);
        return;
    }
    const float* s; __hip_bfloat16* d; int R, Rp;
    if (id < 80)       { s = Wemb; d = WembT; R = DW_;  Rp = DWP_; }
    else if (id < 336) { s = Wcls; d = WclsT; R = DT_;  Rp = DT_;  id -= 80;  }
    else if (id < 528) { s = Wv;   d = WvT;   R = DF_;  Rp = DF_;  id -= 336; }
    else               { s = Wbap; d = WbapT; R = DT_;  Rp = DT_;  id -= 528; }
    int bx = id & 15;
    int by = id >> 4;
    tp_body(s, d, R, DT_, Rp, bx * 64, by * 64);
}

// ---------------------------------------------------------------------------
// MFMA bf16 GEMM: C[M][N] = act(A[M][Kp] @ Bt[N][Kp]^T + bias)
// 128x128 tile, BK=64, global_load_lds w16 with XOR chunk swizzle, coalesced
// LDS epilogue (OUTBF=1), XCD-bijective remap.
template <int RELU, int OUTBF>
__global__ __launch_bounds__(256)
void gemm_mfma(const __hip_bfloat16* __restrict__ A,
               const __hip_bfloat16* __restrict__ Bt,
               const float* __restrict__ bias,
               void* __restrict__ Cout, int M, int N, int Kp) {
    __shared__ __align__(16) char smem[34816];       // max(As+Bs, C-tile 128x136)
    __hip_bfloat16* As = (__hip_bfloat16*)smem;      // [128][64]
    __hip_bfloat16* Bs = As + 128 * 64;              // [128][64]
    int tid = threadIdx.x;
    int wave = tid >> 6, lane = tid & 63;
    int quad = lane >> 4, l16 = lane & 15;
    int wm = (wave & 1) * 64, wn = (wave >> 1) * 64;

    // XCD-aware bijective remap (m204)
    int gx = gridDim.x;
    int nwg = gx * gridDim.y;
    int flat = blockIdx.y * gx + blockIdx.x;
    int q = nwg >> 3, r = nwg & 7;
    int xcd = flat & 7, lid = flat >> 3;
    int o = (xcd < r ? xcd * (q + 1) : r * (q + 1) + (xcd - r) * q) + lid;
    int n0 = (o % gx) * 128;
    int m0 = (o / gx) * 128;

    floatx4 acc[4][4];
    #pragma unroll
    for (int i = 0; i < 4; ++i)
        #pragma unroll
        for (int j = 0; j < 4; ++j)
            acc[i][j] = (floatx4){0.f, 0.f, 0.f, 0.f};

    int rsub = lane >> 3;
    int gchunk = (lane & 7) ^ rsub;

    int arow[4], brow[4];
    #pragma unroll
    for (int i = 0; i < 4; ++i) {
        arow[i] = wm + i * 16 + l16;
        brow[i] = wn + i * 16 + l16;
    }

    for (int k0 = 0; k0 < Kp; k0 += 64) {
        #pragma unroll
        for (int c = 0; c < 4; ++c) {
            int grp = wave * 4 + c;
            int row = grp * 8 + rsub;
            int ra = m0 + row; if (ra >= M) ra = M - 1;   // clamp: junk unused
            gload_lds16(A + (size_t)ra * Kp + k0 + gchunk * 8, As + grp * 512);
            gload_lds16(Bt + (size_t)(n0 + row) * Kp + k0 + gchunk * 8, Bs + grp * 512);
        }
        __syncthreads();
        #pragma unroll
        for (int ks = 0; ks < 2; ++ks) {
            short8 af[4], bf[4];
            #pragma unroll
            for (int mi = 0; mi < 4; ++mi)
                af[mi] = *(const short8*)&As[arow[mi] * 64 +
                            ((((ks << 2) | quad) ^ (arow[mi] & 7)) << 3)];
            #pragma unroll
            for (int ni = 0; ni < 4; ++ni)
                bf[ni] = *(const short8*)&Bs[brow[ni] * 64 +
                            ((((ks << 2) | quad) ^ (brow[ni] & 7)) << 3)];
            #pragma unroll
            for (int mi = 0; mi < 4; ++mi)
                #pragma unroll
                for (int ni = 0; ni < 4; ++ni)
                    acc[mi][ni] = __builtin_amdgcn_mfma_f32_16x16x32_bf16(
                        af[mi], bf[ni], acc[mi][ni], 0, 0, 0);
        }
        __syncthreads();
    }

    // C/D mapping: col = lane&15, row = quad*4 + reg  [measured m89/m91]
    float bn[4];
    #pragma unroll
    for (int ni = 0; ni < 4; ++ni) bn[ni] = bias[n0 + wn + ni * 16 + l16];

    if (OUTBF) {
        __hip_bfloat16* Cs = (__hip_bfloat16*)smem;
        #pragma unroll
        for (int mi = 0; mi < 4; ++mi)
            #pragma unroll
            for (int rr = 0; rr < 4; ++rr) {
                int row = wm + mi * 16 + quad * 4 + rr;
                #pragma unroll
                for (int ni = 0; ni < 4; ++ni) {
                    float val = acc[mi][ni][rr] + bn[ni];
                    if (RELU) val = fmaxf(val, 0.f);
                    Cs[row * 136 + wn + ni * 16 + l16] = (__hip_bfloat16)val;
                }
            }
        __syncthreads();
        #pragma unroll
        for (int j = 0; j < 8; ++j) {
            int ch = tid + 256 * j;              // 2048 chunks of 16 B
            int row = ch >> 4, c16 = ch & 15;
            int r = m0 + row;
            float4 val = *(const float4*)&Cs[row * 136 + c16 * 8];
            if (r < M)
                *(float4*)((__hip_bfloat16*)Cout + (size_t)r * N + n0 + c16 * 8) = val;
        }
    } else {
        #pragma unroll
        for (int mi = 0; mi < 4; ++mi)
            #pragma unroll
            for (int rr = 0; rr < 4; ++rr) {
                int r = m0 + wm + mi * 16 + quad * 4 + rr;
                if (r < M) {
                    #pragma unroll
                    for (int ni = 0; ni < 4; ++ni) {
                        float val = acc[mi][ni][rr] + bn[ni];
                        if (RELU) val = fmaxf(val, 0.f);
                        ((float*)Cout)[(size_t)r * N + n0 + wn + ni * 16 + l16] = val;
                    }
                }
            }
    }
}

// ---------------------------------------------------------------------------
// 4. attn scores via MFMA: s[bc,f,k] = sum_d v[bc,f,d] * cls[b0+bc,k,d].
// Batched mini-GEMM: per block 128 f-rows x 16 k-cols (10 real), K = 1024.
// Same staging geometry / XOR swizzle as gemm_mfma. Replaces the
// shuffle-reduce attn_s kernel (10 dependent 6-deep DS chains per wave).
__global__ __launch_bounds__(256)
void attn_s_mfma(const __hip_bfloat16* __restrict__ v_buf,
                 const __hip_bfloat16* __restrict__ cls,
                 float* __restrict__ s_buf, int b0) {
    __shared__ __align__(16) __hip_bfloat16 As[128 * 64];  // 16 KB
    __shared__ __align__(16) __hip_bfloat16 Bs[16 * 64];   // 2 KB
    int tid = threadIdx.x;
    int wave = tid >> 6, lane = tid & 63;
    int quad = lane >> 4, l16 = lane & 15;
    int bc = blockIdx.y;
    int b = b0 + bc;
    int f0 = blockIdx.x * 128;           // 6 m-tiles cover 768 >= 676
    int wm = wave * 32;                  // each wave: 2 m-frags (32 f rows)

    int rsub = lane >> 3;
    int gchunk = (lane & 7) ^ rsub;

    floatx4 acc[2];
    acc[0] = (floatx4){0.f, 0.f, 0.f, 0.f};
    acc[1] = (floatx4){0.f, 0.f, 0.f, 0.f};

    int arow[2];
    arow[0] = wm + l16;
    arow[1] = wm + 16 + l16;

    for (int k0 = 0; k0 < DT_; k0 += 64) {
        #pragma unroll
        for (int c = 0; c < 4; ++c) {
            int grp = wave * 4 + c;
            int row = grp * 8 + rsub;
            int fa = f0 + row; if (fa >= F_) fa = F_ - 1;   // clamp: junk unused
            gload_lds16(v_buf + ((size_t)bc * F_ + fa) * DT_ + k0 + gchunk * 8,
                        As + grp * 512);
        }
        if (wave == 0) {                 // wave-uniform branch
            #pragma unroll
            for (int c = 0; c < 2; ++c) {
                int row = c * 8 + rsub;  // 0..15
                int rc = row < K_ ? row : K_ - 1;
                gload_lds16(cls + ((size_t)b * K_ + rc) * DT_ + k0 + gchunk * 8,
                            Bs + c * 512);
            }
        }
        __syncthreads();
        #pragma unroll
        for (int ks = 0; ks < 2; ++ks) {
            short8 bf = *(const short8*)&Bs[l16 * 64 +
                            ((((ks << 2) | quad) ^ (l16 & 7)) << 3)];
            #pragma unroll
            for (int mi = 0; mi < 2; ++mi) {
                short8 af = *(const short8*)&As[arow[mi] * 64 +
                                ((((ks << 2) | quad) ^ (arow[mi] & 7)) << 3)];
                acc[mi] = __builtin_amdgcn_mfma_f32_16x16x32_bf16(
                    af, bf, acc[mi], 0, 0, 0);
            }
        }
        __syncthreads();
    }

    // C/D: col = l16 (class k), row = quad*4 + rr (f within frag)
    if (l16 < K_) {
        #pragma unroll
        for (int mi = 0; mi < 2; ++mi)
            #pragma unroll
            for (int rr = 0; rr < 4; ++rr) {
                int f = f0 + wm + mi * 16 + quad * 4 + rr;
                if (f < F_)
                    s_buf[((size_t)bc * F_ + f) * K_ + l16] = acc[mi][rr];
            }
    }
}

// ---------------------------------------------------------------------------
// 5. softmax stats per (bc,k): m = max_f s, rl = 1/sum_f exp(s-m)
__global__ __launch_bounds__(64)
void softmax_stats(const float* __restrict__ s_buf, float2* __restrict__ ml,
                   int b0) {
    int k = blockIdx.x, bc = blockIdx.y, lane = threadIdx.x;
    const float* sp = s_buf + (size_t)bc * F_ * K_ + k;
    float m = -INFINITY;
    for (int f = lane; f < F_; f += 64) m = fmaxf(m, sp[(size_t)f * K_]);
    #pragma unroll
    for (int off = 32; off > 0; off >>= 1) m = fmaxf(m, __shfl_xor(m, off));
    float l = 0.f;
    for (int f = lane; f < F_; f += 64) l += __expf(sp[(size_t)f * K_] - m);
    #pragma unroll
    for (int off = 32; off > 0; off >>= 1) l += __shfl_xor(l, off);
    if (lane == 0) ml[(size_t)(b0 + bc) * K_ + k] = make_float2(m, 1.f / l);
}

// ---------------------------------------------------------------------------
// 6a. partial bap over f-segment, softmax weights computed inline:
//     pp[seg][b][d] = sum_k cls[b,k,d] * sum_{f in seg} w[f,k]*v[bc,f,d]
__global__ __launch_bounds__(256)
void o_bap_partial(const __hip_bfloat16* __restrict__ v_buf,
                   const float* __restrict__ s_buf,
                   const float2* __restrict__ ml,
                   const __hip_bfloat16* __restrict__ cls,
                   float* __restrict__ pp, int b0) {
    int bc = blockIdx.x, seg = blockIdx.y;
    int b = b0 + bc;
    int t = threadIdx.x;
    int f0 = seg * FSEG;
    __shared__ float wbuf[FSEG * K_];          // 520 floats
    __shared__ float mk[K_], rlk[K_];
    __shared__ float red[128 * 8];             // half-1 partial outputs
    if (t < K_) {
        float2 v = ml[(size_t)b * K_ + t];
        mk[t] = v.x; rlk[t] = v.y;
    }
    __syncthreads();
    for (int j = t; j < FSEG * K_; j += 256) {
        int k = j % K_;
        float sv = s_buf[((size_t)bc * F_ + f0) * K_ + j];
        wbuf[j] = __expf(sv - mk[k]) * rlk[k];
    }
    __syncthreads();
    int th = t & 127, half = t >> 7;
    int d0 = th * 8;
    int fs = half * (FSEG / 2);                // 0 or 26
    float acc[K_][8] = {};
    const __hip_bfloat16* vp = v_buf + ((size_t)bc * F_ + f0 + fs) * DT_ + d0;
    for (int f = 0; f < FSEG / 2; ++f) {
        union { float4 f4; __hip_bfloat16 h[8]; } u;
        u.f4 = *(const float4*)(vp + (size_t)f * DT_);
        float vv[8];
        #pragma unroll
        for (int i = 0; i < 8; ++i) vv[i] = (float)u.h[i];
        const float* wk = &wbuf[(fs + f) * K_];
        #pragma unroll
        for (int k = 0; k < K_; ++k)
            #pragma unroll
            for (int i = 0; i < 8; ++i) acc[k][i] += wk[k] * vv[i];
    }
    float outv[8] = {};
    union { float4 f4; __hip_bfloat16 h[8]; } cu;
    #pragma unroll
    for (int k = 0; k < K_; ++k) {
        cu.f4 = *(const float4*)(cls + ((size_t)b * K_ + k) * DT_ + d0);
        #pragma unroll
        for (int i = 0; i < 8; ++i) outv[i] += acc[k][i] * (float)cu.h[i];
    }
    if (half == 1) {
        *(float4*)&red[th * 8]     = *(float4*)&outv[0];
        *(float4*)&red[th * 8 + 4] = *(float4*)&outv[4];
    }
    __syncthreads();
    if (half == 0) {
        #pragma unroll
        for (int i = 0; i < 8; ++i) outv[i] += red[th * 8 + i];
        float* pd = pp + ((size_t)seg * B_ + b) * DT_ + d0;
        *(float4*)pd       = *(float4*)&outv[0];
        *(float4*)(pd + 4) = *(float4*)&outv[4];
    }
}

// 6b. combine segments -> bf16 bap
__global__ void bap_combine(const float* __restrict__ pp,
                            __hip_bfloat16* __restrict__ bap) {
    int idx = blockIdx.x * 256 + threadIdx.x;   // B_*DT_ total
    float s = 0.f;
    #pragma unroll
    for (int g = 0; g < NSEG; ++g) s += pp[idx + (size_t)g * B_ * DT_];
    bap[idx] = (__hip_bfloat16)s;
}

// ---------------------------------------------------------------------------
// 7. lg[b,k] = y[b,:] @ W_fc[:,k] + b_fc[k]; scatter into out
__global__ void final_kernel(const float* __restrict__ y,
                             const float* __restrict__ Wfc,
                             const float* __restrict__ bfc,
                             const int* __restrict__ topk_idx,
                             float* __restrict__ out) {
    int b = blockIdx.x, tid = threadIdx.x;
    int lane = tid & 63, wave = tid >> 6;
    float pk[K_] = {};
    for (int d = tid; d < DT_; d += 256) {
        float yv = y[(size_t)b * DT_ + d];
        #pragma unroll
        for (int k = 0; k < K_; ++k) pk[k] += yv * Wfc[(size_t)d * K_ + k];
    }
    __shared__ float wsum[4][K_];
    #pragma unroll
    for (int k = 0; k < K_; ++k) {
        float a = pk[k];
        #pragma unroll
        for (int off = 32; off > 0; off >>= 1) a += __shfl_down(a, off);
        if (lane == 0) wsum[wave][k] = a;
    }
    __syncthreads();
    if (tid < K_) {
        float lg = wsum[0][tid] + wsum[1][tid] + wsum[2][tid] + wsum[3][tid] + bfc[tid];
        out[(size_t)b * C_ + topk_idx[b * K_ + tid]] = lg;
    }
}

// ---------------------------------------------------------------------------
extern "C" void kernel_launch(void* const* d_in, const int* in_sizes, int n_in,
                              void* d_out, int out_size, void* d_ws, size_t ws_size,
                              hipStream_t stream) {
    const float* ftm           = (const float*)d_in[0];
    const float* logits        = (const float*)d_in[1];
    const int*   indices_table = (const int*)d_in[3];
    const float* word2vec      = (const float*)d_in[4];
    const float* W_emb         = (const float*)d_in[5];
    const float* b_emb         = (const float*)d_in[6];
    const float* W_cls         = (const float*)d_in[7];
    const float* b_cls         = (const float*)d_in[8];
    const float* W_v           = (const float*)d_in[9];
    const float* b_v           = (const float*)d_in[10];
    const float* W_bap         = (const float*)d_in[11];
    const float* b_bap         = (const float*)d_in[12];
    const float* W_fc          = (const float*)d_in[13];
    const float* b_fc          = (const float*)d_in[14];
    float* out = (float*)d_out;

    char* ws = (char*)d_ws;
    size_t off = 0;
    auto alloc = [&](size_t bytes) -> void* {
        void* p = ws + off;
        off = (off + bytes + 255) & ~(size_t)255;
        return p;
    };
    int*            topk_idx = (int*)           alloc((size_t)B_ * K_ * 4);
    __hip_bfloat16* emb_bf   = (__hip_bfloat16*)alloc((size_t)B_ * K_ * DWP_ * 2);
    __hip_bfloat16* cls1     = (__hip_bfloat16*)alloc((size_t)B_ * K_ * DT_ * 2);
    __hip_bfloat16* cls2     = (__hip_bfloat16*)alloc((size_t)B_ * K_ * DT_ * 2);
    __hip_bfloat16* Wemb_t   = (__hip_bfloat16*)alloc((size_t)DT_ * DWP_ * 2);
    __hip_bfloat16* Wcls_t   = (__hip_bfloat16*)alloc((size_t)DT_ * DT_ * 2);
    __hip_bfloat16* Wv_t     = (__hip_bfloat16*)alloc((size_t)DT_ * DF_ * 2);
    __hip_bfloat16* Wbap_t   = (__hip_bfloat16*)alloc((size_t)DT_ * DT_ * 2);
    float*          s_buf    = (float*)         alloc((size_t)B_ * F_ * K_ * 4);
    float2*         ml       = (float2*)        alloc((size_t)B_ * K_ * 8);
    float*          pp       = (float*)         alloc((size_t)NSEG * B_ * DT_ * 4);
    __hip_bfloat16* bap_bf   = (__hip_bfloat16*)alloc((size_t)B_ * DT_ * 2);
    float*          yb       = (float*)         alloc((size_t)B_ * DT_ * 4);

    // dynamic batch-chunk: fit ftm_t + v for nb batches in remaining ws
    size_t per_b = (size_t)F_ * DF_ * 2 + (size_t)F_ * DT_ * 2;
    size_t avail = (ws_size > off + 8192) ? ws_size - off - 8192 : 0;
    int nb = (int)(avail / per_b);
    if (nb > B_) nb = B_;
    if (nb < 1) nb = 1;
    __hip_bfloat16* ftm_t = (__hip_bfloat16*)alloc((size_t)nb * F_ * DF_ * 2);
    __hip_bfloat16* v_buf = (__hip_bfloat16*)alloc((size_t)nb * F_ * DT_ * 2);

    hipMemsetAsync(d_out, 0, (size_t)out_size * sizeof(float), stream);

    topk_emb_kernel<<<B_, 256, 0, stream>>>(logits, indices_table, word2vec,
                                            topk_idx, emb_bf);

    if (nb == B_) {
        transpose_all<<<784 + 132 * B_, 256, 0, stream>>>(
            W_emb, Wemb_t, W_cls, Wcls_t, W_v, Wv_t, W_bap, Wbap_t, ftm, ftm_t);
    } else {
        transpose_weights<<<784, 256, 0, stream>>>(
            W_emb, Wemb_t, W_cls, Wcls_t, W_v, Wv_t, W_bap, Wbap_t);
    }

    // cls path (MFMA, n-fastest grid)
    gemm_mfma<1, 1><<<dim3(DT_ / 128, (B_ * K_ + 127) / 128), 256, 0, stream>>>(
        emb_bf, Wemb_t, b_emb, cls1, B_ * K_, DT_, DWP_);
    gemm_mfma<1, 1><<<dim3(DT_ / 128, (B_ * K_ + 127) / 128), 256, 0, stream>>>(
        cls1, Wcls_t, b_cls, cls2, B_ * K_, DT_, DT_);

    // main path, chunked only if ws is small (nb == 64 -> single pass)
    for (int b0 = 0; b0 < B_; b0 += nb) {
        int cb = min(nb, B_ - b0);
        if (nb != B_) {
            transpose_ftm<<<dim3((F_ + 63) / 64, DF_ / 64, cb), 256, 0, stream>>>(
                ftm + (size_t)b0 * DF_ * F_, ftm_t);
        }
        int M = cb * F_;
        gemm_mfma<1, 1><<<dim3(DT_ / 128, (M + 127) / 128), 256, 0, stream>>>(
            ftm_t, Wv_t, b_v, v_buf, M, DT_, DF_);
        float* s_c = s_buf + (size_t)b0 * F_ * K_;
        attn_s_mfma<<<dim3((F_ + 127) / 128, cb), 256, 0, stream>>>(
            v_buf, cls2, s_c, b0);
        softmax_stats<<<dim3(K_, cb), 64, 0, stream>>>(s_c, ml, b0);
        o_bap_partial<<<dim3(cb, NSEG), 256, 0, stream>>>(
            v_buf, s_c, ml, cls2, pp, b0);
    }
    bap_combine<<<B_ * DT_ / 256, 256, 0, stream>>>(pp, bap_bf);

    gemm_mfma<1, 0><<<dim3(DT_ / 128, 1), 256, 0, stream>>>(
        bap_bf, Wbap_t, b_bap, yb, B_, DT_, DT_);
    final_kernel<<<B_, 256, 0, stream>>>(yb, W_fc, b_fc, topk_idx, out);
}